// Round 7
// baseline (183.314 us; speedup 1.0000x reference)
//
#include <hip/hip_runtime.h>
#include <hip/hip_bf16.h>
#include <hip/hip_fp16.h>
#include <math.h>

// ---- problem constants (structural, from the reference) ----
#define NB      2
#define QN      12240
#define HW_TOT  12240
#define DIMS    256
#define HEADS   8
#define CH      32
#define LEVELS  4
#define POINTS  4
#define M_TOT   (NB * QN)        // 24480

typedef unsigned short ushort_t;
typedef __attribute__((ext_vector_type(8))) short short8;
typedef __attribute__((ext_vector_type(4))) float floatx4;

__device__ __forceinline__ ushort_t f2bf(float f) {
    __hip_bfloat16 h = __float2bfloat16(f);
    return *reinterpret_cast<ushort_t*>(&h);
}
__device__ __forceinline__ ushort_t f2h(float f) {
    __half h = __float2half(f);
    return *reinterpret_cast<ushort_t*>(&h);
}

#define GLOAD16(gp, lp) __builtin_amdgcn_global_load_lds( \
    (const __attribute__((address_space(1))) void*)(gp),  \
    (__attribute__((address_space(3))) void*)(lp), 16, 0, 0)

// =====================================================================
// Weights -> transposed bf16 (small, 384 blocks): Tin/Tout (gi<65536),
// Tcomb [384][256], combined bias, and the 128B zero pad after vproj.
// =====================================================================
__global__ __launch_bounds__(256) void prep_weights_kernel(
    const float* __restrict__ W_in, const float* __restrict__ W_off,
    const float* __restrict__ W_attn, const float* __restrict__ W_out,
    const float* __restrict__ b_off, const float* __restrict__ b_attn,
    ushort_t* __restrict__ Tin, ushort_t* __restrict__ Tcomb,
    ushort_t* __restrict__ Tout, float* __restrict__ bcomb,
    int* __restrict__ vpad)
{
    const int gi = blockIdx.x * 256 + threadIdx.x;   // grid = 384 blocks
    if (gi < 32)  vpad[gi] = 0;                      // 128B zero pad
    if (gi < 384) bcomb[gi] = (gi < 256) ? b_off[gi] : b_attn[gi - 256];
    const int k = gi & 255;                          // coalesced along k
    const int n = gi >> 8;
    if (gi < 65536) {
        Tin[n * 256 + k]  = f2bf(W_in[k * 256 + n]);
        Tout[n * 256 + k] = f2bf(W_out[k * 256 + n]);
    }
    const float val = (n < 256) ? W_off[k * 256 + n]
                                : W_attn[k * 128 + (n - 256)];
    Tcomb[n * 256 + k] = f2bf(val);
}

// =====================================================================
// Fused-convert GEMM tile with 2-PHASE PREFETCH (T3 minimum pattern):
// double-buffered LDS; tile t+1's B gload_lds + A fp32 reg-loads are
// issued BEFORE computing tile t, so HBM latency hides under MFMA.
// A cvt+ds_write for t+1 happens AFTER MFMA(t) (T14 split: compiler's
// auto-wait for the A-regs lands post-MFMA, not before).  All cross-
// wave visibility still guarded by full __syncthreads (race-safe).
// CMODE: 1 = bf16 HEAD-MAJOR ((h*M+row)*32+ch), 2 = fp16 row-major.
// =====================================================================
template<int CMODE, bool DUAL>
__device__ __forceinline__ void gemm_fused_tile(
    const float* __restrict__ A32, const ushort_t* __restrict__ BT,
    const float* __restrict__ bias, void* __restrict__ C,
    int M, int Nc, int bm0, int bn0a, int bn0b,
    ushort_t* AsB, ushort_t* Bs0B, ushort_t* Bs1B)
{
    const int tid  = threadIdx.x;
    const int wave = tid >> 6;
    const int lane = tid & 63;
    const int quad = lane >> 4;
    const int l16  = lane & 15;
    const int wm   = (wave >> 1) * 64;
    const int wn   = (wave & 1) * 64;

    const int off0 = tid * 16;            // LDS byte offset (linear)
    const int row0 = off0 >> 6;           // 0..63 (64B = 32 bf16/row)
    const int kc0  = (off0 & 63) >> 1;    // element k-offset: 0/8/16/24

    int ar0 = bm0 + row0;      if (ar0 > M - 1) ar0 = M - 1;
    int ar1 = bm0 + row0 + 64; if (ar1 > M - 1) ar1 = M - 1;

    const float*    gA0  = A32 + (size_t)ar0 * 256 + kc0;
    const float*    gA1  = A32 + (size_t)ar1 * 256 + kc0;
    const ushort_t* gb0a = BT + (size_t)(bn0a + row0) * 256 + kc0;
    const ushort_t* gb1a = BT + (size_t)(bn0a + row0 + 64) * 256 + kc0;
    const ushort_t* gb0b = BT + (size_t)(bn0b + row0) * 256 + kc0;
    const ushort_t* gb1b = BT + (size_t)(bn0b + row0 + 64) * 256 + kc0;

    floatx4 acc0[4][4], acc1[4][4];
    #pragma unroll
    for (int i = 0; i < 4; ++i)
        #pragma unroll
        for (int j = 0; j < 4; ++j) {
            acc0[i][j] = (floatx4){0.f, 0.f, 0.f, 0.f};
            if (DUAL) acc1[i][j] = (floatx4){0.f, 0.f, 0.f, 0.f};
        }

    float4 arg[4];   // staged A fp32 regs for the NEXT tile

    // ---- prologue: stage tile 0 ----
    {
        ushort_t* l0 = Bs0B + wave * 512;
        GLOAD16(gb0a, l0); GLOAD16(gb1a, l0 + 2048);
        if (DUAL) {
            ushort_t* l1 = Bs1B + wave * 512;
            GLOAD16(gb0b, l1); GLOAD16(gb1b, l1 + 2048);
        }
        arg[0] = *(const float4*)(gA0);     arg[1] = *(const float4*)(gA0 + 4);
        arg[2] = *(const float4*)(gA1);     arg[3] = *(const float4*)(gA1 + 4);
        ushort_t t0[8] = {f2bf(arg[0].x), f2bf(arg[0].y), f2bf(arg[0].z), f2bf(arg[0].w),
                          f2bf(arg[1].x), f2bf(arg[1].y), f2bf(arg[1].z), f2bf(arg[1].w)};
        ushort_t t1[8] = {f2bf(arg[2].x), f2bf(arg[2].y), f2bf(arg[2].z), f2bf(arg[2].w),
                          f2bf(arg[3].x), f2bf(arg[3].y), f2bf(arg[3].z), f2bf(arg[3].w)};
        *(int4*)&AsB[tid * 8]        = *(int4*)t0;
        *(int4*)&AsB[tid * 8 + 2048] = *(int4*)t1;
    }
    __syncthreads();

    #pragma unroll
    for (int t = 0; t < 8; ++t) {
        const int cur = t & 1;
        const int kkn = (t + 1) * 32;
        // issue next tile's loads BEFORE compute (prefetch under MFMA)
        if (t < 7) {
            ushort_t* l0 = Bs0B + (cur ^ 1) * 4096 + wave * 512;
            GLOAD16(gb0a + kkn, l0); GLOAD16(gb1a + kkn, l0 + 2048);
            if (DUAL) {
                ushort_t* l1 = Bs1B + (cur ^ 1) * 4096 + wave * 512;
                GLOAD16(gb0b + kkn, l1); GLOAD16(gb1b + kkn, l1 + 2048);
            }
            arg[0] = *(const float4*)(gA0 + kkn);
            arg[1] = *(const float4*)(gA0 + kkn + 4);
            arg[2] = *(const float4*)(gA1 + kkn);
            arg[3] = *(const float4*)(gA1 + kkn + 4);
        }

        const ushort_t* As  = AsB  + cur * 4096;
        const ushort_t* Bs0 = Bs0B + cur * 4096;
        const ushort_t* Bs1 = Bs1B + cur * 4096;
        short8 af[4], bfa[4], bfb[4];
        #pragma unroll
        for (int mt = 0; mt < 4; ++mt)
            af[mt] = *(const short8*)&As[(wm + mt * 16 + l16) * 32 + quad * 8];
        #pragma unroll
        for (int nt = 0; nt < 4; ++nt) {
            bfa[nt] = *(const short8*)&Bs0[(wn + nt * 16 + l16) * 32 + quad * 8];
            if (DUAL)
                bfb[nt] = *(const short8*)&Bs1[(wn + nt * 16 + l16) * 32 + quad * 8];
        }
        #pragma unroll
        for (int mt = 0; mt < 4; ++mt)
            #pragma unroll
            for (int nt = 0; nt < 4; ++nt) {
                acc0[mt][nt] = __builtin_amdgcn_mfma_f32_16x16x32_bf16(
                    af[mt], bfa[nt], acc0[mt][nt], 0, 0, 0);
                if (DUAL)
                    acc1[mt][nt] = __builtin_amdgcn_mfma_f32_16x16x32_bf16(
                        af[mt], bfb[nt], acc1[mt][nt], 0, 0, 0);
            }

        // convert + ds_write the prefetched A AFTER the MFMAs (T14)
        if (t < 7) {
            ushort_t t0[8] = {f2bf(arg[0].x), f2bf(arg[0].y), f2bf(arg[0].z), f2bf(arg[0].w),
                              f2bf(arg[1].x), f2bf(arg[1].y), f2bf(arg[1].z), f2bf(arg[1].w)};
            ushort_t t1[8] = {f2bf(arg[2].x), f2bf(arg[2].y), f2bf(arg[2].z), f2bf(arg[2].w),
                              f2bf(arg[3].x), f2bf(arg[3].y), f2bf(arg[3].z), f2bf(arg[3].w)};
            ushort_t* Asn = AsB + (cur ^ 1) * 4096;
            *(int4*)&Asn[tid * 8]        = *(int4*)t0;
            *(int4*)&Asn[tid * 8 + 2048] = *(int4*)t1;
        }
        __syncthreads();
    }

    #pragma unroll
    for (int mt = 0; mt < 4; ++mt) {
        #pragma unroll
        for (int j = 0; j < 4; ++j) {
            const int row = bm0 + wm + mt * 16 + quad * 4 + j;
            if (row >= M) continue;
            #pragma unroll
            for (int nt = 0; nt < 4; ++nt) {
                {
                    const int col = bn0a + wn + nt * 16 + l16;
                    const float val = acc0[mt][nt][j] + bias[col];
                    if (CMODE == 1) {
                        const size_t idx = (((size_t)(col >> 5) * M + row) << 5) + (col & 31);
                        ((ushort_t*)C)[idx] = f2bf(val);
                    } else {
                        ((ushort_t*)C)[(size_t)row * Nc + col] = f2h(val);
                    }
                }
                if (DUAL) {
                    const int col = bn0b + wn + nt * 16 + l16;
                    const float val = acc1[mt][nt][j] + bias[col];
                    if (CMODE == 1) {
                        const size_t idx = (((size_t)(col >> 5) * M + row) << 5) + (col & 31);
                        ((ushort_t*)C)[idx] = f2bf(val);
                    } else {
                        ((ushort_t*)C)[(size_t)row * Nc + col] = f2h(val);
                    }
                }
            }
        }
    }
}

__global__ __launch_bounds__(256) void gemm_proj_kernel(
    const float* __restrict__ v, const float* __restrict__ q,
    const ushort_t* __restrict__ Tin, const ushort_t* __restrict__ Tcomb,
    const float* __restrict__ b_in, const float* __restrict__ bcomb,
    ushort_t* __restrict__ vproj, ushort_t* __restrict__ offh)
{
    __shared__ ushort_t As [2 * 128 * 32];
    __shared__ ushort_t Bs0[2 * 128 * 32];
    __shared__ ushort_t Bs1[2 * 128 * 32];
    const int bm0 = blockIdx.x * 128;
    const int y = blockIdx.y;
    if (y == 0)       // vproj = v @ W_in (bf16 head-major), both col-tiles
        gemm_fused_tile<1, true >(v, Tin,   b_in,  vproj, M_TOT, 256, bm0, 0, 128, As, Bs0, Bs1);
    else if (y == 1)  // offh cols 0-255 = q @ Tcomb (fp16)
        gemm_fused_tile<2, true >(q, Tcomb, bcomb, offh,  M_TOT, 384, bm0, 0, 128, As, Bs0, Bs1);
    else              // offh cols 256-383
        gemm_fused_tile<2, false>(q, Tcomb, bcomb, offh,  M_TOT, 384, bm0, 256, 0, As, Bs0, Bs1);
}

// =====================================================================
// Output GEMM with the same 2-phase prefetch (all-gload_lds, dbuf LDS).
// =====================================================================
__device__ __forceinline__ void gemm_tile_core(
    const ushort_t* __restrict__ A, const ushort_t* __restrict__ BT,
    const float* __restrict__ bias, float* __restrict__ C,
    int M, int Nc, int bm0, int bn0, int K,
    ushort_t* AsB, ushort_t* BsB)
{
    const int tid  = threadIdx.x;
    const int wave = tid >> 6;
    const int lane = tid & 63;
    const int quad = lane >> 4;
    const int l16  = lane & 15;
    const int wm   = (wave >> 1) * 64;
    const int wn   = (wave & 1) * 64;

    const int off0 = tid * 16;
    const int row0 = off0 >> 6;
    const int kc0  = (off0 & 63) >> 1;

    int ar0 = bm0 + row0;      if (ar0 > M - 1) ar0 = M - 1;
    int ar1 = bm0 + row0 + 64; if (ar1 > M - 1) ar1 = M - 1;

    const ushort_t* ga0 = A  + (size_t)ar0 * K + kc0;
    const ushort_t* ga1 = A  + (size_t)ar1 * K + kc0;
    const ushort_t* gb0 = BT + (size_t)(bn0 + row0) * K + kc0;
    const ushort_t* gb1 = BT + (size_t)(bn0 + row0 + 64) * K + kc0;

    floatx4 acc[4][4];
    #pragma unroll
    for (int i = 0; i < 4; ++i)
        #pragma unroll
        for (int j = 0; j < 4; ++j)
            acc[i][j] = (floatx4){0.f, 0.f, 0.f, 0.f};

    // prologue: stage tile 0
    {
        ushort_t* lA = AsB + wave * 512;
        ushort_t* lB = BsB + wave * 512;
        GLOAD16(ga0, lA); GLOAD16(ga1, lA + 2048);
        GLOAD16(gb0, lB); GLOAD16(gb1, lB + 2048);
    }
    __syncthreads();

    #pragma unroll
    for (int t = 0; t < 8; ++t) {
        const int cur = t & 1;
        const int kkn = (t + 1) * 32;
        if (t < 7) {       // prefetch next tile before compute
            ushort_t* lA = AsB + (cur ^ 1) * 4096 + wave * 512;
            ushort_t* lB = BsB + (cur ^ 1) * 4096 + wave * 512;
            GLOAD16(ga0 + kkn, lA); GLOAD16(ga1 + kkn, lA + 2048);
            GLOAD16(gb0 + kkn, lB); GLOAD16(gb1 + kkn, lB + 2048);
        }

        const ushort_t* As = AsB + cur * 4096;
        const ushort_t* Bs = BsB + cur * 4096;
        short8 af[4], bfr[4];
        #pragma unroll
        for (int mt = 0; mt < 4; ++mt)
            af[mt] = *(const short8*)&As[(wm + mt * 16 + l16) * 32 + quad * 8];
        #pragma unroll
        for (int nt = 0; nt < 4; ++nt)
            bfr[nt] = *(const short8*)&Bs[(wn + nt * 16 + l16) * 32 + quad * 8];
        #pragma unroll
        for (int mt = 0; mt < 4; ++mt)
            #pragma unroll
            for (int nt = 0; nt < 4; ++nt)
                acc[mt][nt] = __builtin_amdgcn_mfma_f32_16x16x32_bf16(
                    af[mt], bfr[nt], acc[mt][nt], 0, 0, 0);
        __syncthreads();
    }

    #pragma unroll
    for (int mt = 0; mt < 4; ++mt) {
        #pragma unroll
        for (int j = 0; j < 4; ++j) {
            const int row = bm0 + wm + mt * 16 + quad * 4 + j;
            if (row >= M) continue;
            #pragma unroll
            for (int nt = 0; nt < 4; ++nt) {
                const int col = bn0 + wn + nt * 16 + l16;
                C[(size_t)row * Nc + col] = acc[mt][nt][j] + bias[col];
            }
        }
    }
}

__global__ __launch_bounds__(256) void gemm_out_kernel(
    const ushort_t* __restrict__ mid, const ushort_t* __restrict__ Tout,
    const float* __restrict__ b_out, float* __restrict__ out)
{
    __shared__ ushort_t As[2 * 128 * 32];
    __shared__ ushort_t Bs[2 * 128 * 32];
    gemm_tile_core(mid, Tout, b_out, out, M_TOT, 256,
                   blockIdx.x * 128, blockIdx.y * 128, 256, As, Bs);
}

// =====================================================================
// Sampling kernel v8 (unchanged from R5/R6): head-split + XCD locality
// + fp16 offlog; paired-corner 128B gathers; zeroed-pad overread safety.
// =====================================================================
#define LO32(u) __uint_as_float((u) << 16)
#define HI32(u) __uint_as_float((u) & 0xffff0000u)
#define ACC8(W, g) \
    a0 = fmaf(W, LO32(g.x), a0);  a1 = fmaf(W, HI32(g.x), a1); \
    a2 = fmaf(W, LO32(g.y), a2);  a3 = fmaf(W, HI32(g.y), a3); \
    a4 = fmaf(W, LO32(g.z), a4);  a5 = fmaf(W, HI32(g.z), a5); \
    a6 = fmaf(W, LO32(g.w), a6);  a7 = fmaf(W, HI32(g.w), a7);

__global__ __launch_bounds__(256, 8) void msda_sample_kernel(
    const ushort_t* __restrict__ vproj, const ushort_t* __restrict__ offh,
    const float* __restrict__ p, ushort_t* __restrict__ mid)
{
    __shared__ int4 s_main[4][68];       // [wave][h4*17 + s]
    __shared__ int2 s_aux[4][68];

    const int tid = threadIdx.x;
    const int wv  = tid >> 6;            // wave id 0..3
    const int l   = tid & 63;
    const int idx = blockIdx.x;
    const int b8  = idx & 7;             // XCD id (round-robin assumption)
    const int hh  = b8 >> 2;             // head half: XCD 0-3 -> 0, 4-7 -> 1
    const int qg  = (idx >> 3) * 4 + (b8 & 3);
    const int nq  = qg * 4 + wv;
    const int nb  = (nq >= QN) ? 1 : 0;

    // ---- phase 1: lane = sample (h4 = l>>4, lvl = (l>>2)&3, pt = l&3)
    const size_t orow = (size_t)nq * 384;
    const __half2 o2 = *(const __half2*)&offh[orow + hh * 128 + 2 * l];
    const float2  of = __half22float2(o2);
    const float   lg = __half2float(
        *(const __half*)&offh[orow + 256 + hh * 64 + l]);
    const int     lvl = (l >> 2) & 3;
    const float2  pl  = *(const float2*)&p[(size_t)nq * 8 + lvl * 2];

    // softmax over 16-lane head groups
    float mx = lg;
    #pragma unroll
    for (int m = 8; m; m >>= 1) mx = fmaxf(mx, __shfl_xor(mx, m));
    const float e = __expf(lg - mx);
    float ss = e;
    #pragma unroll
    for (int m = 8; m; m >>= 1) ss += __shfl_xor(ss, m);
    const float wt = e * __builtin_amdgcn_rcpf(ss);

    const int   Wl = 96 >> lvl;                     // H == W per level
    const float fW = (float)Wl;
    const int   st = 12288 - (12288 >> (2 * lvl));  // level start pixel
    const int   h4 = l >> 4;
    const int   h  = hh * 4 + h4;                   // global head

    {
        const float x  = fmaf(pl.x, fW, of.x) - 0.5f;
        const float y  = fmaf(pl.y, fW, of.y) - 0.5f;
        const float xf = floorf(x), yf = floorf(y);
        const float dx = x - xf,    dy = y - yf;
        const int   x0 = (int)xf,   y0 = (int)yf;
        const bool vxl = (unsigned)x0       < (unsigned)Wl;
        const bool vxr = (unsigned)(x0 + 1) < (unsigned)Wl;
        const bool vy0 = (unsigned)y0       < (unsigned)Wl;
        const bool vy1 = (unsigned)(y0 + 1) < (unsigned)Wl;

        const float wxl = vxl ? (1.0f - dx) : (vxr ? dx : 0.0f);
        const float wxr = (vxl && vxr) ? dx : 0.0f;
        const int   xb  = vxl ? x0 : 0;

        const float wy0f = wt * (1.0f - dy), wy1f = wt * dy;
        const float w_l0 = vy0 ? wxl * wy0f : 0.0f;
        const float w_r0 = vy0 ? wxr * wy0f : 0.0f;
        const float w_l1 = vy1 ? wxl * wy1f : 0.0f;
        const float w_r1 = vy1 ? wxr * wy1f : 0.0f;

        int yc0 = y0;     if (yc0 < 0) yc0 = 0; if (yc0 > Wl - 1) yc0 = Wl - 1;
        int yc1 = y0 + 1; if (yc1 < 0) yc1 = 0; if (yc1 > Wl - 1) yc1 = Wl - 1;

        const int rowb = h * M_TOT + nb * HW_TOT + st + xb;
        const int lin0 = rowb + yc0 * Wl;   // valid pixel-head index
        const int lin1 = rowb + yc1 * Wl;   // (final pixel's right chunk
                                            //  reads the zeroed pad, w=0)
        const int e17 = h4 * 17 + (l & 15);
        s_main[wv][e17] = (int4){lin0 << 6, __float_as_int(w_l0),
                                 __float_as_int(w_r0), lin1 << 6};
        s_aux[wv][e17]  = (int2){__float_as_int(w_l1), __float_as_int(w_r1)};
    }

    // wave-local LDS handoff: DS ops are in-order per wave; drain lgkm
    // and fence the compiler.  No s_barrier -- waves are independent.
    __builtin_amdgcn_wave_barrier();
    asm volatile("s_waitcnt lgkmcnt(0)" ::: "memory");
    __builtin_amdgcn_wave_barrier();

    // ---- phase 2: lane = (head hg, row r, corner, ch-quad)
    const int hg     = l >> 4;           // head within half
    const int rowr   = (l >> 3) & 1;
    const int corner = (l >> 2) & 1;
    const int c16    = (l & 7) * 16;     // byte offset within 128B pair
    const char* __restrict__ vb = (const char*)vproj;

    float a0 = 0.f, a1 = 0.f, a2 = 0.f, a3 = 0.f;
    float a4 = 0.f, a5 = 0.f, a6 = 0.f, a7 = 0.f;

    #pragma unroll 4
    for (int t = 0; t < 16; ++t) {
        const int  e17 = hg * 17 + t;
        const int4 c   = s_main[wv][e17];   // {b0, wl0, wr0, b1}
        const int2 cb  = s_aux[wv][e17];    // {wl1, wr1}
        const int  base = rowr ? c.w : c.x;
        const float wl  = rowr ? __int_as_float(cb.x) : __int_as_float(c.y);
        const float wr  = rowr ? __int_as_float(cb.y) : __int_as_float(c.z);
        const float w   = corner ? wr : wl;
        const uint4 g   = *(const uint4*)(vb + (unsigned)(base + c16));
        ACC8(w, g);
    }

    // fold corners (bit2) then rows (bit3)
    a0 += __shfl_xor(a0, 4);  a1 += __shfl_xor(a1, 4);
    a2 += __shfl_xor(a2, 4);  a3 += __shfl_xor(a3, 4);
    a4 += __shfl_xor(a4, 4);  a5 += __shfl_xor(a5, 4);
    a6 += __shfl_xor(a6, 4);  a7 += __shfl_xor(a7, 4);
    a0 += __shfl_xor(a0, 8);  a1 += __shfl_xor(a1, 8);
    a2 += __shfl_xor(a2, 8);  a3 += __shfl_xor(a3, 8);
    a4 += __shfl_xor(a4, 8);  a5 += __shfl_xor(a5, 8);
    a6 += __shfl_xor(a6, 8);  a7 += __shfl_xor(a7, 8);

    if ((l & 12) == 0) {                 // 4 writer lanes per head
        ushort_t mv[8] = {f2bf(a0), f2bf(a1), f2bf(a2), f2bf(a3),
                          f2bf(a4), f2bf(a5), f2bf(a6), f2bf(a7)};
        const int col = (hh * 4 + hg) * 32 + (l & 3) * 8;
        *(uint4*)&mid[(size_t)nq * 256 + col] = *(uint4*)mv;
    }
}

// =====================================================================
extern "C" void kernel_launch(void* const* d_in, const int* in_sizes, int n_in,
                              void* d_out, int out_size, void* d_ws, size_t ws_size,
                              hipStream_t stream)
{
    const float* q      = (const float*)d_in[0];
    const float* p      = (const float*)d_in[1];
    const float* v      = (const float*)d_in[2];
    const float* W_off  = (const float*)d_in[3];
    const float* b_off  = (const float*)d_in[4];
    const float* W_attn = (const float*)d_in[5];
    const float* b_attn = (const float*)d_in[6];
    const float* W_in   = (const float*)d_in[7];
    const float* b_in   = (const float*)d_in[8];
    const float* W_out  = (const float*)d_in[9];
    const float* b_out  = (const float*)d_in[10];
    float* out = (float*)d_out;

    const int M = M_TOT;                            // 24480

    // workspace layout.  vproj is followed by a 128B ZEROED pad
    // (sampler overread safety).
    ushort_t* vproj  = (ushort_t*)d_ws;                          // M*256 bf16 (head-major)
    ushort_t* vpad   = vproj + (size_t)M * 256;                  // 64 ushort = 128B zero pad
    ushort_t* offh   = vpad + 64;                                // M*384 fp16
    ushort_t* mid    = offh + (size_t)M * 384;                   // M*256 bf16
    ushort_t* Tin    = mid + (size_t)M * 256;
    ushort_t* Tcomb  = Tin + 256 * 256;
    ushort_t* Tout   = Tcomb + 384 * 256;
    float*    bcomb  = (float*)(Tout + 256 * 256);

    // 0) weight transposes/fusion + pad zero (small)
    prep_weights_kernel<<<dim3(384), 256, 0, stream>>>(
        W_in, W_off, W_attn, W_out, b_off, b_attn,
        Tin, Tcomb, Tout, bcomb, (int*)vpad);

    // 1) fused convert+projection GEMMs (2-phase prefetch)
    gemm_proj_kernel<<<dim3(192, 3), 256, 0, stream>>>(
        v, q, Tin, Tcomb, b_in, bcomb, vproj, offh);
    // 2) softmax + bilinear sampling -> bf16 mid (head-split, XCD-local)
    msda_sample_kernel<<<dim3(12240), 256, 0, stream>>>(vproj, offh, p, mid);
    // 3) out = mid @ W_out + b_out (2-phase prefetch)
    gemm_out_kernel<<<dim3(192, 2), 256, 0, stream>>>(mid, Tout, b_out, out);
}

// Round 8
// 181.409 us; speedup vs baseline: 1.0105x; 1.0105x over previous
//
#include <hip/hip_runtime.h>
#include <hip/hip_bf16.h>
#include <hip/hip_fp16.h>
#include <math.h>

// ---- problem constants (structural, from the reference) ----
#define NB      2
#define QN      12240
#define HW_TOT  12240
#define DIMS    256
#define HEADS   8
#define CH      32
#define LEVELS  4
#define POINTS  4
#define M_TOT   (NB * QN)        // 24480

typedef unsigned short ushort_t;
typedef __attribute__((ext_vector_type(8))) short short8;
typedef __attribute__((ext_vector_type(4))) float floatx4;

__device__ __forceinline__ ushort_t f2bf(float f) {
    __hip_bfloat16 h = __float2bfloat16(f);
    return *reinterpret_cast<ushort_t*>(&h);
}
__device__ __forceinline__ ushort_t f2h(float f) {
    __half h = __float2half(f);
    return *reinterpret_cast<ushort_t*>(&h);
}

#define GLOAD16(gp, lp) __builtin_amdgcn_global_load_lds( \
    (const __attribute__((address_space(1))) void*)(gp),  \
    (__attribute__((address_space(3))) void*)(lp), 16, 0, 0)

// =====================================================================
// Weights -> transposed bf16 (small, 384 blocks): Tin/Tout (gi<65536),
// Tcomb [384][256], combined bias, and the 128B zero pad after vproj.
// =====================================================================
__global__ __launch_bounds__(256) void prep_weights_kernel(
    const float* __restrict__ W_in, const float* __restrict__ W_off,
    const float* __restrict__ W_attn, const float* __restrict__ W_out,
    const float* __restrict__ b_off, const float* __restrict__ b_attn,
    ushort_t* __restrict__ Tin, ushort_t* __restrict__ Tcomb,
    ushort_t* __restrict__ Tout, float* __restrict__ bcomb,
    int* __restrict__ vpad)
{
    const int gi = blockIdx.x * 256 + threadIdx.x;   // grid = 384 blocks
    if (gi < 32)  vpad[gi] = 0;                      // 128B zero pad
    if (gi < 384) bcomb[gi] = (gi < 256) ? b_off[gi] : b_attn[gi - 256];
    const int k = gi & 255;                          // coalesced along k
    const int n = gi >> 8;
    if (gi < 65536) {
        Tin[n * 256 + k]  = f2bf(W_in[k * 256 + n]);
        Tout[n * 256 + k] = f2bf(W_out[k * 256 + n]);
    }
    const float val = (n < 256) ? W_off[k * 256 + n]
                                : W_attn[k * 128 + (n - 256)];
    Tcomb[n * 256 + k] = f2bf(val);
}

// =====================================================================
// Fused-convert GEMM tile (R6 single-buffer structure -- the R7 2-phase
// prefetch was reverted: 96KB LDS dropped proj to 1 block/CU, net 0).
// A is RAW FP32 (v or q) converted to bf16 in registers during staging.
// DUAL: two 128-col tiles share one A-pass (32 MFMA per barrier-pair).
// CMODE: 1 = FP16 HEAD-MAJOR vproj ((h*M+row)*32+ch)  [fp16 so the
//            sampler can use v_fma_mix_f32 -- and fp16 quantizes
//            N(0,1) values BETTER than bf16], 2 = fp16 row-major offh.
// =====================================================================
template<int CMODE, bool DUAL>
__device__ __forceinline__ void gemm_fused_tile(
    const float* __restrict__ A32, const ushort_t* __restrict__ BT,
    const float* __restrict__ bias, void* __restrict__ C,
    int M, int Nc, int bm0, int bn0a, int bn0b,
    ushort_t* As, ushort_t* Bs0, ushort_t* Bs1)
{
    const int tid  = threadIdx.x;
    const int wave = tid >> 6;
    const int lane = tid & 63;
    const int quad = lane >> 4;
    const int l16  = lane & 15;
    const int wm   = (wave >> 1) * 64;
    const int wn   = (wave & 1) * 64;

    const int off0 = tid * 16;            // LDS byte offset (linear)
    const int row0 = off0 >> 6;           // 0..63 (64B = 32 bf16/row)
    const int kc0  = (off0 & 63) >> 1;    // element k-offset: 0/8/16/24

    int ar0 = bm0 + row0;      if (ar0 > M - 1) ar0 = M - 1;
    int ar1 = bm0 + row0 + 64; if (ar1 > M - 1) ar1 = M - 1;

    const float*    gA0  = A32 + (size_t)ar0 * 256 + kc0;
    const float*    gA1  = A32 + (size_t)ar1 * 256 + kc0;
    const ushort_t* gb0a = BT + (size_t)(bn0a + row0) * 256 + kc0;
    const ushort_t* gb1a = BT + (size_t)(bn0a + row0 + 64) * 256 + kc0;
    const ushort_t* gb0b = BT + (size_t)(bn0b + row0) * 256 + kc0;
    const ushort_t* gb1b = BT + (size_t)(bn0b + row0 + 64) * 256 + kc0;

    ushort_t* lB0a = Bs0 + wave * 512;
    ushort_t* lB1a = Bs0 + wave * 512 + 2048;
    ushort_t* lB0b = Bs1 + wave * 512;
    ushort_t* lB1b = Bs1 + wave * 512 + 2048;

    floatx4 acc0[4][4], acc1[4][4];
    #pragma unroll
    for (int i = 0; i < 4; ++i)
        #pragma unroll
        for (int j = 0; j < 4; ++j) {
            acc0[i][j] = (floatx4){0.f, 0.f, 0.f, 0.f};
            if (DUAL) acc1[i][j] = (floatx4){0.f, 0.f, 0.f, 0.f};
        }

    for (int kk = 0; kk < 256; kk += 32) {
        __builtin_amdgcn_global_load_lds(
            (const __attribute__((address_space(1))) void*)(gb0a + kk),
            (__attribute__((address_space(3))) void*)lB0a, 16, 0, 0);
        __builtin_amdgcn_global_load_lds(
            (const __attribute__((address_space(1))) void*)(gb1a + kk),
            (__attribute__((address_space(3))) void*)lB1a, 16, 0, 0);
        if (DUAL) {
            __builtin_amdgcn_global_load_lds(
                (const __attribute__((address_space(1))) void*)(gb0b + kk),
                (__attribute__((address_space(3))) void*)lB0b, 16, 0, 0);
            __builtin_amdgcn_global_load_lds(
                (const __attribute__((address_space(1))) void*)(gb1b + kk),
                (__attribute__((address_space(3))) void*)lB1b, 16, 0, 0);
        }
        // A: fp32 -> bf16 reg-staged (each thread: 2 rows x 8 elems)
        {
            const float4 a0 = *(const float4*)(gA0 + kk);
            const float4 a1 = *(const float4*)(gA0 + kk + 4);
            const float4 b0 = *(const float4*)(gA1 + kk);
            const float4 b1 = *(const float4*)(gA1 + kk + 4);
            ushort_t t0[8] = {f2bf(a0.x), f2bf(a0.y), f2bf(a0.z), f2bf(a0.w),
                              f2bf(a1.x), f2bf(a1.y), f2bf(a1.z), f2bf(a1.w)};
            ushort_t t1[8] = {f2bf(b0.x), f2bf(b0.y), f2bf(b0.z), f2bf(b0.w),
                              f2bf(b1.x), f2bf(b1.y), f2bf(b1.z), f2bf(b1.w)};
            *(int4*)&As[tid * 8]        = *(int4*)t0;
            *(int4*)&As[tid * 8 + 2048] = *(int4*)t1;
        }
        __syncthreads();

        short8 af[4], bfa[4], bfb[4];
        #pragma unroll
        for (int mt = 0; mt < 4; ++mt)
            af[mt] = *(const short8*)&As[(wm + mt * 16 + l16) * 32 + quad * 8];
        #pragma unroll
        for (int nt = 0; nt < 4; ++nt) {
            bfa[nt] = *(const short8*)&Bs0[(wn + nt * 16 + l16) * 32 + quad * 8];
            if (DUAL)
                bfb[nt] = *(const short8*)&Bs1[(wn + nt * 16 + l16) * 32 + quad * 8];
        }
        #pragma unroll
        for (int mt = 0; mt < 4; ++mt)
            #pragma unroll
            for (int nt = 0; nt < 4; ++nt) {
                acc0[mt][nt] = __builtin_amdgcn_mfma_f32_16x16x32_bf16(
                    af[mt], bfa[nt], acc0[mt][nt], 0, 0, 0);
                if (DUAL)
                    acc1[mt][nt] = __builtin_amdgcn_mfma_f32_16x16x32_bf16(
                        af[mt], bfb[nt], acc1[mt][nt], 0, 0, 0);
            }
        __syncthreads();
    }

    #pragma unroll
    for (int mt = 0; mt < 4; ++mt) {
        #pragma unroll
        for (int j = 0; j < 4; ++j) {
            const int row = bm0 + wm + mt * 16 + quad * 4 + j;
            if (row >= M) continue;
            #pragma unroll
            for (int nt = 0; nt < 4; ++nt) {
                {
                    const int col = bn0a + wn + nt * 16 + l16;
                    const float val = acc0[mt][nt][j] + bias[col];
                    if (CMODE == 1) {
                        const size_t idx = (((size_t)(col >> 5) * M + row) << 5) + (col & 31);
                        ((ushort_t*)C)[idx] = f2h(val);          // fp16 vproj
                    } else {
                        ((ushort_t*)C)[(size_t)row * Nc + col] = f2h(val);
                    }
                }
                if (DUAL) {
                    const int col = bn0b + wn + nt * 16 + l16;
                    const float val = acc1[mt][nt][j] + bias[col];
                    if (CMODE == 1) {
                        const size_t idx = (((size_t)(col >> 5) * M + row) << 5) + (col & 31);
                        ((ushort_t*)C)[idx] = f2h(val);          // fp16 vproj
                    } else {
                        ((ushort_t*)C)[(size_t)row * Nc + col] = f2h(val);
                    }
                }
            }
        }
    }
}

__global__ __launch_bounds__(256) void gemm_proj_kernel(
    const float* __restrict__ v, const float* __restrict__ q,
    const ushort_t* __restrict__ Tin, const ushort_t* __restrict__ Tcomb,
    const float* __restrict__ b_in, const float* __restrict__ bcomb,
    ushort_t* __restrict__ vproj, ushort_t* __restrict__ offh)
{
    __shared__ ushort_t As [128 * 32];
    __shared__ ushort_t Bs0[128 * 32];
    __shared__ ushort_t Bs1[128 * 32];
    const int bm0 = blockIdx.x * 128;
    const int y = blockIdx.y;
    if (y == 0)       // vproj = v @ W_in (fp16 head-major), both col-tiles
        gemm_fused_tile<1, true >(v, Tin,   b_in,  vproj, M_TOT, 256, bm0, 0, 128, As, Bs0, Bs1);
    else if (y == 1)  // offh cols 0-255 = q @ Tcomb (fp16)
        gemm_fused_tile<2, true >(q, Tcomb, bcomb, offh,  M_TOT, 384, bm0, 0, 128, As, Bs0, Bs1);
    else              // offh cols 256-383
        gemm_fused_tile<2, false>(q, Tcomb, bcomb, offh,  M_TOT, 384, bm0, 256, 0, As, Bs0, Bs1);
}

// =====================================================================
// m97-style bf16 GEMM for the output projection (R6 single-buffer).
// =====================================================================
__device__ __forceinline__ void gemm_tile_core(
    const ushort_t* __restrict__ A, const ushort_t* __restrict__ BT,
    const float* __restrict__ bias, float* __restrict__ C,
    int M, int Nc, int bm0, int bn0, int K,
    ushort_t* As, ushort_t* Bs)
{
    const int tid  = threadIdx.x;
    const int wave = tid >> 6;
    const int lane = tid & 63;
    const int quad = lane >> 4;
    const int l16  = lane & 15;
    const int wm   = (wave >> 1) * 64;
    const int wn   = (wave & 1) * 64;

    const int off0 = tid * 16;
    const int row0 = off0 >> 6;
    const int kc0  = (off0 & 63) >> 1;

    int ar0 = bm0 + row0;      if (ar0 > M - 1) ar0 = M - 1;
    int ar1 = bm0 + row0 + 64; if (ar1 > M - 1) ar1 = M - 1;

    const ushort_t* ga0 = A  + (size_t)ar0 * K + kc0;
    const ushort_t* ga1 = A  + (size_t)ar1 * K + kc0;
    const ushort_t* gb0 = BT + (size_t)(bn0 + row0) * K + kc0;
    const ushort_t* gb1 = BT + (size_t)(bn0 + row0 + 64) * K + kc0;

    ushort_t* lA0 = As + wave * 512;
    ushort_t* lA1 = As + wave * 512 + 2048;
    ushort_t* lB0 = Bs + wave * 512;
    ushort_t* lB1 = Bs + wave * 512 + 2048;

    floatx4 acc[4][4];
    #pragma unroll
    for (int i = 0; i < 4; ++i)
        #pragma unroll
        for (int j = 0; j < 4; ++j)
            acc[i][j] = (floatx4){0.f, 0.f, 0.f, 0.f};

    for (int kk = 0; kk < K; kk += 32) {
        GLOAD16(ga0 + kk, lA0);
        GLOAD16(ga1 + kk, lA1);
        GLOAD16(gb0 + kk, lB0);
        GLOAD16(gb1 + kk, lB1);
        __syncthreads();

        short8 af[4], bfr[4];
        #pragma unroll
        for (int mt = 0; mt < 4; ++mt)
            af[mt] = *(const short8*)&As[(wm + mt * 16 + l16) * 32 + quad * 8];
        #pragma unroll
        for (int nt = 0; nt < 4; ++nt)
            bfr[nt] = *(const short8*)&Bs[(wn + nt * 16 + l16) * 32 + quad * 8];
        #pragma unroll
        for (int mt = 0; mt < 4; ++mt)
            #pragma unroll
            for (int nt = 0; nt < 4; ++nt)
                acc[mt][nt] = __builtin_amdgcn_mfma_f32_16x16x32_bf16(
                    af[mt], bfr[nt], acc[mt][nt], 0, 0, 0);
        __syncthreads();
    }

    #pragma unroll
    for (int mt = 0; mt < 4; ++mt) {
        #pragma unroll
        for (int j = 0; j < 4; ++j) {
            const int row = bm0 + wm + mt * 16 + quad * 4 + j;
            if (row >= M) continue;
            #pragma unroll
            for (int nt = 0; nt < 4; ++nt) {
                const int col = bn0 + wn + nt * 16 + l16;
                C[(size_t)row * Nc + col] = acc[mt][nt][j] + bias[col];
            }
        }
    }
}

__global__ __launch_bounds__(256) void gemm_out_kernel(
    const ushort_t* __restrict__ mid, const ushort_t* __restrict__ Tout,
    const float* __restrict__ b_out, float* __restrict__ out)
{
    __shared__ ushort_t As[128 * 32];
    __shared__ ushort_t Bs[128 * 32];
    gemm_tile_core(mid, Tout, b_out, out, M_TOT, 256,
                   blockIdx.x * 128, blockIdx.y * 128, 256, As, Bs);
}

// =====================================================================
// Sampling kernel v9: as v8 (head-split + XCD locality + fp16 offlog,
// paired-corner 128B gathers, zeroed-pad overread safety) but vproj is
// FP16 -> inner loop uses fmaf(w, __half2float(h), acc), which the
// compiler folds to v_fma_mix_f32 (1 VALU op per channel instead of
// bf16's unpack+fma = 2).  f32 accumulation unchanged.
// =====================================================================
#define ACC8(W, g) { \
    const __half2 h0 = *(const __half2*)&(g).x; \
    const __half2 h1 = *(const __half2*)&(g).y; \
    const __half2 h2 = *(const __half2*)&(g).z; \
    const __half2 h3 = *(const __half2*)&(g).w; \
    a0 = fmaf(W, __low2float(h0),  a0);  a1 = fmaf(W, __high2float(h0), a1); \
    a2 = fmaf(W, __low2float(h1),  a2);  a3 = fmaf(W, __high2float(h1), a3); \
    a4 = fmaf(W, __low2float(h2),  a4);  a5 = fmaf(W, __high2float(h2), a5); \
    a6 = fmaf(W, __low2float(h3),  a6);  a7 = fmaf(W, __high2float(h3), a7); }

__global__ __launch_bounds__(256, 8) void msda_sample_kernel(
    const ushort_t* __restrict__ vproj, const ushort_t* __restrict__ offh,
    const float* __restrict__ p, ushort_t* __restrict__ mid)
{
    __shared__ int4 s_main[4][68];       // [wave][h4*17 + s]
    __shared__ int2 s_aux[4][68];

    const int tid = threadIdx.x;
    const int wv  = tid >> 6;            // wave id 0..3
    const int l   = tid & 63;
    const int idx = blockIdx.x;
    const int b8  = idx & 7;             // XCD id (round-robin assumption)
    const int hh  = b8 >> 2;             // head half: XCD 0-3 -> 0, 4-7 -> 1
    const int qg  = (idx >> 3) * 4 + (b8 & 3);
    const int nq  = qg * 4 + wv;
    const int nb  = (nq >= QN) ? 1 : 0;

    // ---- phase 1: lane = sample (h4 = l>>4, lvl = (l>>2)&3, pt = l&3)
    const size_t orow = (size_t)nq * 384;
    const __half2 o2 = *(const __half2*)&offh[orow + hh * 128 + 2 * l];
    const float2  of = __half22float2(o2);
    const float   lg = __half2float(
        *(const __half*)&offh[orow + 256 + hh * 64 + l]);
    const int     lvl = (l >> 2) & 3;
    const float2  pl  = *(const float2*)&p[(size_t)nq * 8 + lvl * 2];

    // softmax over 16-lane head groups
    float mx = lg;
    #pragma unroll
    for (int m = 8; m; m >>= 1) mx = fmaxf(mx, __shfl_xor(mx, m));
    const float e = __expf(lg - mx);
    float ss = e;
    #pragma unroll
    for (int m = 8; m; m >>= 1) ss += __shfl_xor(ss, m);
    const float wt = e * __builtin_amdgcn_rcpf(ss);

    const int   Wl = 96 >> lvl;                     // H == W per level
    const float fW = (float)Wl;
    const int   st = 12288 - (12288 >> (2 * lvl));  // level start pixel
    const int   h4 = l >> 4;
    const int   h  = hh * 4 + h4;                   // global head

    {
        const float x  = fmaf(pl.x, fW, of.x) - 0.5f;
        const float y  = fmaf(pl.y, fW, of.y) - 0.5f;
        const float xf = floorf(x), yf = floorf(y);
        const float dx = x - xf,    dy = y - yf;
        const int   x0 = (int)xf,   y0 = (int)yf;
        const bool vxl = (unsigned)x0       < (unsigned)Wl;
        const bool vxr = (unsigned)(x0 + 1) < (unsigned)Wl;
        const bool vy0 = (unsigned)y0       < (unsigned)Wl;
        const bool vy1 = (unsigned)(y0 + 1) < (unsigned)Wl;

        const float wxl = vxl ? (1.0f - dx) : (vxr ? dx : 0.0f);
        const float wxr = (vxl && vxr) ? dx : 0.0f;
        const int   xb  = vxl ? x0 : 0;

        const float wy0f = wt * (1.0f - dy), wy1f = wt * dy;
        const float w_l0 = vy0 ? wxl * wy0f : 0.0f;
        const float w_r0 = vy0 ? wxr * wy0f : 0.0f;
        const float w_l1 = vy1 ? wxl * wy1f : 0.0f;
        const float w_r1 = vy1 ? wxr * wy1f : 0.0f;

        int yc0 = y0;     if (yc0 < 0) yc0 = 0; if (yc0 > Wl - 1) yc0 = Wl - 1;
        int yc1 = y0 + 1; if (yc1 < 0) yc1 = 0; if (yc1 > Wl - 1) yc1 = Wl - 1;

        const int rowb = h * M_TOT + nb * HW_TOT + st + xb;
        const int lin0 = rowb + yc0 * Wl;   // valid pixel-head index
        const int lin1 = rowb + yc1 * Wl;   // (final pixel's right chunk
                                            //  reads the zeroed pad, w=0)
        const int e17 = h4 * 17 + (l & 15);
        s_main[wv][e17] = (int4){lin0 << 6, __float_as_int(w_l0),
                                 __float_as_int(w_r0), lin1 << 6};
        s_aux[wv][e17]  = (int2){__float_as_int(w_l1), __float_as_int(w_r1)};
    }

    // wave-local LDS handoff: DS ops are in-order per wave; drain lgkm
    // and fence the compiler.  No s_barrier -- waves are independent.
    __builtin_amdgcn_wave_barrier();
    asm volatile("s_waitcnt lgkmcnt(0)" ::: "memory");
    __builtin_amdgcn_wave_barrier();

    // ---- phase 2: lane = (head hg, row r, corner, ch-quad)
    const int hg     = l >> 4;           // head within half
    const int rowr   = (l >> 3) & 1;
    const int corner = (l >> 2) & 1;
    const int c16    = (l & 7) * 16;     // byte offset within 128B pair
    const char* __restrict__ vb = (const char*)vproj;

    float a0 = 0.f, a1 = 0.f, a2 = 0.f, a3 = 0.f;
    float a4 = 0.f, a5 = 0.f, a6 = 0.f, a7 = 0.f;

    #pragma unroll 4
    for (int t = 0; t < 16; ++t) {
        const int  e17 = hg * 17 + t;
        const int4 c   = s_main[wv][e17];   // {b0, wl0, wr0, b1}
        const int2 cb  = s_aux[wv][e17];    // {wl1, wr1}
        const int  base = rowr ? c.w : c.x;
        const float wl  = rowr ? __int_as_float(cb.x) : __int_as_float(c.y);
        const float wr  = rowr ? __int_as_float(cb.y) : __int_as_float(c.z);
        const float w   = corner ? wr : wl;
        const uint4 g   = *(const uint4*)(vb + (unsigned)(base + c16));
        ACC8(w, g);
    }

    // fold corners (bit2) then rows (bit3)
    a0 += __shfl_xor(a0, 4);  a1 += __shfl_xor(a1, 4);
    a2 += __shfl_xor(a2, 4);  a3 += __shfl_xor(a3, 4);
    a4 += __shfl_xor(a4, 4);  a5 += __shfl_xor(a5, 4);
    a6 += __shfl_xor(a6, 4);  a7 += __shfl_xor(a7, 4);
    a0 += __shfl_xor(a0, 8);  a1 += __shfl_xor(a1, 8);
    a2 += __shfl_xor(a2, 8);  a3 += __shfl_xor(a3, 8);
    a4 += __shfl_xor(a4, 8);  a5 += __shfl_xor(a5, 8);
    a6 += __shfl_xor(a6, 8);  a7 += __shfl_xor(a7, 8);

    if ((l & 12) == 0) {                 // 4 writer lanes per head
        ushort_t mv[8] = {f2bf(a0), f2bf(a1), f2bf(a2), f2bf(a3),
                          f2bf(a4), f2bf(a5), f2bf(a6), f2bf(a7)};
        const int col = (hh * 4 + hg) * 32 + (l & 3) * 8;
        *(uint4*)&mid[(size_t)nq * 256 + col] = *(uint4*)mv;
    }
}

// =====================================================================
extern "C" void kernel_launch(void* const* d_in, const int* in_sizes, int n_in,
                              void* d_out, int out_size, void* d_ws, size_t ws_size,
                              hipStream_t stream)
{
    const float* q      = (const float*)d_in[0];
    const float* p      = (const float*)d_in[1];
    const float* v      = (const float*)d_in[2];
    const float* W_off  = (const float*)d_in[3];
    const float* b_off  = (const float*)d_in[4];
    const float* W_attn = (const float*)d_in[5];
    const float* b_attn = (const float*)d_in[6];
    const float* W_in   = (const float*)d_in[7];
    const float* b_in   = (const float*)d_in[8];
    const float* W_out  = (const float*)d_in[9];
    const float* b_out  = (const float*)d_in[10];
    float* out = (float*)d_out;

    const int M = M_TOT;                            // 24480

    // workspace layout.  vproj (fp16 head-major) is followed by a 128B
    // ZEROED pad (sampler overread safety; fp16 zero = 0x0000).
    ushort_t* vproj  = (ushort_t*)d_ws;                          // M*256 fp16 (head-major)
    ushort_t* vpad   = vproj + (size_t)M * 256;                  // 64 ushort = 128B zero pad
    ushort_t* offh   = vpad + 64;                                // M*384 fp16
    ushort_t* mid    = offh + (size_t)M * 384;                   // M*256 bf16
    ushort_t* Tin    = mid + (size_t)M * 256;
    ushort_t* Tcomb  = Tin + 256 * 256;
    ushort_t* Tout   = Tcomb + 384 * 256;
    float*    bcomb  = (float*)(Tout + 256 * 256);

    // 0) weight transposes/fusion + pad zero (small)
    prep_weights_kernel<<<dim3(384), 256, 0, stream>>>(
        W_in, W_off, W_attn, W_out, b_off, b_attn,
        Tin, Tcomb, Tout, bcomb, (int*)vpad);

    // 1) fused convert+projection GEMMs (reads RAW fp32 v/q)
    gemm_proj_kernel<<<dim3(192, 3), 256, 0, stream>>>(
        v, q, Tin, Tcomb, b_in, bcomb, vproj, offh);
    // 2) softmax + bilinear sampling -> bf16 mid (fp16 vproj, fma_mix)
    msda_sample_kernel<<<dim3(12240), 256, 0, stream>>>(vproj, offh, p, mid);
    // 3) out = mid @ W_out + b_out
    gemm_out_kernel<<<dim3(192, 2), 256, 0, stream>>>(mid, Tout, b_out, out);
}